// Round 2
// baseline (882.127 us; speedup 1.0000x reference)
//
#include <hip/hip_runtime.h>

#define N_NODES  50000
#define N_EDGES  500000
#define DIM      128
#define N_GRAPHS 256

// ---------------------------------------------------------------------------
// Edge scatter-aggregate: agg[dst[e]][d] += feat[src[e]][d]  (f32)
// One thread per (edge, feature). 64M atomics into a 25.6MB L2/L3-resident buf.
// ---------------------------------------------------------------------------
__global__ void scatter_kernel(const float* __restrict__ feat,
                               const int* __restrict__ src,
                               const int* __restrict__ dst,
                               float* __restrict__ agg)
{
    int idx = blockIdx.x * blockDim.x + threadIdx.x;
    int e = idx >> 7;
    int d = idx & 127;
    if (e < N_EDGES) {
        int s = src[e];
        int t = dst[e];
        float v = feat[s * DIM + d];
        atomicAdd(&agg[t * DIM + d], v);
    }
}

// ---------------------------------------------------------------------------
// Fused dual GEMM + bias + ReLU:
//   H[n][j] = relu( sum_d Aagg[n][d]*Wrel[j][d] + sum_d Ax[n][d]*Wroot[j][d] + b[j] )
// Tile: 64 rows x 128 cols per block, 256 threads (16x16), 4x8 acc per thread.
// K chunked in 32s (chunks 0-3: agg/Wrel, 4-7: x/Wroot) through LDS.
// ---------------------------------------------------------------------------
__global__ __launch_bounds__(256)
void gemm_fused(const float* __restrict__ Aagg, const float* __restrict__ Ax,
                const float* __restrict__ Wrel, const float* __restrict__ Wroot,
                const float* __restrict__ bias, float* __restrict__ Hout)
{
    __shared__ float a_s[64][33];    // [row][d-in-chunk], +1 pad
    __shared__ float w_s[32][132];   // [d-in-chunk][col],  +4 pad

    const int row0 = blockIdx.x * 64;
    const int t  = threadIdx.x;
    const int tx = t & 15;   // col group: cols tx*8 .. tx*8+7
    const int ty = t >> 4;   // row group: rows ty*4 .. ty*4+3

    float acc[4][8];
#pragma unroll
    for (int r = 0; r < 4; ++r)
#pragma unroll
        for (int c = 0; c < 8; ++c) acc[r][c] = 0.f;

    for (int kc = 0; kc < 8; ++kc) {
        const float* Asrc = (kc < 4) ? Aagg : Ax;
        const int dbase = (kc & 3) * 32;
        // ---- stage A chunk: 64 rows x 32 d ----
#pragma unroll
        for (int i = 0; i < 8; ++i) {
            int idx = t + i * 256;          // 0..2047
            int r  = idx >> 5;
            int dd = idx & 31;
            int row = row0 + r;
            float v = 0.f;
            if (row < N_NODES) v = Asrc[row * DIM + dbase + dd];
            a_s[r][dd] = v;
        }
        // ---- stage W chunk transposed: w_s[dd][j] = W[j][dbase+dd] ----
        const float* Wm = (kc < 4) ? Wrel : Wroot;
#pragma unroll
        for (int i = 0; i < 16; ++i) {
            int idx = t + i * 256;          // 0..4095
            int j  = idx >> 5;
            int dd = idx & 31;
            w_s[dd][j] = Wm[j * DIM + dbase + dd];
        }
        __syncthreads();

        // ---- compute ----
#pragma unroll
        for (int dd = 0; dd < 32; ++dd) {
            float av[4], wv[8];
#pragma unroll
            for (int r = 0; r < 4; ++r) av[r] = a_s[ty * 4 + r][dd];
#pragma unroll
            for (int c = 0; c < 8; ++c) wv[c] = w_s[dd][tx * 8 + c];
#pragma unroll
            for (int r = 0; r < 4; ++r)
#pragma unroll
                for (int c = 0; c < 8; ++c)
                    acc[r][c] = fmaf(av[r], wv[c], acc[r][c]);
        }
        __syncthreads();
    }

    // ---- epilogue: bias + relu + store ----
#pragma unroll
    for (int r = 0; r < 4; ++r) {
        int row = row0 + ty * 4 + r;
        if (row < N_NODES) {
#pragma unroll
            for (int c = 0; c < 8; ++c) {
                int j = tx * 8 + c;
                float v = acc[r][c] + bias[j];
                Hout[row * DIM + j] = v > 0.f ? v : 0.f;
            }
        }
    }
}

// ---------------------------------------------------------------------------
// Global mean pool, stage 1: per-graph sums + counts via atomics.
// ---------------------------------------------------------------------------
__global__ void pool_kernel(const float* __restrict__ h, const int* __restrict__ batch,
                            float* __restrict__ pooled, float* __restrict__ cnts)
{
    int idx = blockIdx.x * blockDim.x + threadIdx.x;
    int n = idx >> 7;
    int d = idx & 127;
    if (n < N_NODES) {
        int g = batch[n];
        atomicAdd(&pooled[g * DIM + d], h[n * DIM + d]);
        if (d == 0) atomicAdd(&cnts[g], 1.0f);
    }
}

// ---------------------------------------------------------------------------
// Final: out[g] = dot(pooled[g], W_out)/max(cnt,1) + b_out. One wave per graph.
// ---------------------------------------------------------------------------
__global__ void finalize_kernel(const float* __restrict__ pooled, const float* __restrict__ cnts,
                                const float* __restrict__ Wout, const float* __restrict__ bout,
                                float* __restrict__ out)
{
    int g = blockIdx.x;
    int lane = threadIdx.x;  // 0..63
    float s = pooled[g * DIM + lane]      * Wout[lane]
            + pooled[g * DIM + 64 + lane] * Wout[64 + lane];
#pragma unroll
    for (int off = 32; off > 0; off >>= 1) s += __shfl_xor(s, off, 64);
    if (lane == 0) {
        float c = cnts[g];
        c = c > 1.f ? c : 1.f;
        out[g] = s / c + bout[0];
    }
}

extern "C" void kernel_launch(void* const* d_in, const int* in_sizes, int n_in,
                              void* d_out, int out_size, void* d_ws, size_t ws_size,
                              hipStream_t stream)
{
    const float* x       = (const float*)d_in[0];
    const int*   ei      = (const int*)d_in[1];   // [2][E]: row 0 = src, row 1 = dst
    const int*   batch   = (const int*)d_in[2];
    const float* W1_rel  = (const float*)d_in[3];
    const float* W1_root = (const float*)d_in[4];
    const float* b1      = (const float*)d_in[5];
    const float* W2_rel  = (const float*)d_in[6];
    const float* W2_root = (const float*)d_in[7];
    const float* b2      = (const float*)d_in[8];
    const float* W_out   = (const float*)d_in[9];
    const float* b_out   = (const float*)d_in[10];
    float* out = (float*)d_out;

    const int* src  = ei;
    const int* dstv = ei + N_EDGES;

    // Workspace layout (bytes):
    //   agg    @ 0           : N*128*4   = 25,600,000 (f32 accum, reused both layers)
    //   h1     @ 25,600,000  : N*128*4   = 25,600,000 (f32; layer-2 output in-place)
    //   pooled @ 51,200,000  : 256*128*4 = 131,072
    //   cnts   @ 51,331,072  : 256*4     = 1,024
    char* ws = (char*)d_ws;
    float* agg    = (float*)ws;
    float* h1     = (float*)(ws + 25600000);
    float* pooled = (float*)(ws + 51200000);
    float* cnts   = (float*)(ws + 51331072);

    const size_t agg_bytes = (size_t)N_NODES * DIM * sizeof(float);

    // Layer 1
    hipMemsetAsync(agg, 0, agg_bytes, stream);
    scatter_kernel<<<(N_EDGES * 128) / 256, 256, 0, stream>>>(x, src, dstv, agg);
    gemm_fused<<<(N_NODES + 63) / 64, 256, 0, stream>>>(agg, x, W1_rel, W1_root, b1, h1);

    // Layer 2 (agg reused; h2 written in-place over h1 — each block only touches its own rows)
    hipMemsetAsync(agg, 0, agg_bytes, stream);
    scatter_kernel<<<(N_EDGES * 128) / 256, 256, 0, stream>>>(h1, src, dstv, agg);
    gemm_fused<<<(N_NODES + 63) / 64, 256, 0, stream>>>(agg, h1, W2_rel, W2_root, b2, h1);

    // Mean pool + output head
    hipMemsetAsync(pooled, 0, (size_t)(N_GRAPHS * DIM + N_GRAPHS) * sizeof(float), stream);
    pool_kernel<<<(N_NODES * 128 + 255) / 256, 256, 0, stream>>>(h1, batch, pooled, cnts);
    finalize_kernel<<<N_GRAPHS, 64, 0, stream>>>(pooled, cnts, W_out, b_out, out);
}

// Round 3
// 484.258 us; speedup vs baseline: 1.8216x; 1.8216x over previous
//
#include <hip/hip_runtime.h>

#define N_NODES  50000
#define N_EDGES  500000
#define DIM      128
#define N_GRAPHS 256

// ===========================================================================
// CSR build (edge list is the same for both layers -> build once per call)
// ===========================================================================
__global__ void hist_kernel(const int* __restrict__ dst, int* __restrict__ deg)
{
    int e = blockIdx.x * blockDim.x + threadIdx.x;
    if (e < N_EDGES) atomicAdd(&deg[dst[e]], 1);
}

// Single-block exclusive scan of deg[50000] -> row_ptr[50001]; also rewrites
// deg[] in place with the exclusive prefix so it doubles as the build cursor.
__global__ __launch_bounds__(1024)
void scan_kernel(int* __restrict__ deg, int* __restrict__ row_ptr)
{
    const int CHUNK = 49;                       // 1024*49 = 50176 >= 50000
    __shared__ int sums[1024];
    int t = threadIdx.x;
    int base = t * CHUNK;

    int local = 0;
    for (int i = 0; i < CHUNK; ++i) {
        int idx = base + i;
        if (idx < N_NODES) local += deg[idx];
    }
    sums[t] = local;
    __syncthreads();
    for (int off = 1; off < 1024; off <<= 1) {  // Hillis-Steele inclusive scan
        int v = (t >= off) ? sums[t - off] : 0;
        __syncthreads();
        sums[t] += v;
        __syncthreads();
    }
    int run = sums[t] - local;                  // exclusive prefix for my chunk
    for (int i = 0; i < CHUNK; ++i) {
        int idx = base + i;
        if (idx < N_NODES) {
            int d = deg[idx];
            row_ptr[idx] = run;
            deg[idx] = run;                     // cursor for build_kernel
            run += d;
        }
    }
    if (t == 1023) row_ptr[N_NODES] = run;      // = N_EDGES
}

__global__ void build_kernel(const int* __restrict__ src, const int* __restrict__ dst,
                             int* __restrict__ cursor, int* __restrict__ edge_src)
{
    int e = blockIdx.x * blockDim.x + threadIdx.x;
    if (e < N_EDGES) {
        int pos = atomicAdd(&cursor[dst[e]], 1);
        edge_src[pos] = src[e];
    }
}

// ===========================================================================
// Gather-aggregate: one wave per node, lane holds 2 features (float2).
// agg[n][:] = sum over in-edges of feat[src][:]   -- no atomics, no memset.
// ===========================================================================
__global__ __launch_bounds__(256)
void gather_kernel(const float* __restrict__ feat,
                   const int* __restrict__ row_ptr,
                   const int* __restrict__ edge_src,
                   float* __restrict__ agg)
{
    int wid  = (blockIdx.x * blockDim.x + threadIdx.x) >> 6;
    int lane = threadIdx.x & 63;
    int node = __builtin_amdgcn_readfirstlane(wid);   // wave-uniform -> SGPR

    const float2* f2 = (const float2*)feat;
    int e  = row_ptr[node];
    int e1 = row_ptr[node + 1];

    float2 a0 = make_float2(0.f, 0.f), a1 = make_float2(0.f, 0.f);
    for (; e + 1 < e1; e += 2) {                      // 2x unroll for load ILP
        int sa = edge_src[e], sb = edge_src[e + 1];   // wave-uniform scalar loads
        float2 va = f2[sa * 64 + lane];
        float2 vb = f2[sb * 64 + lane];
        a0.x += va.x; a0.y += va.y;
        a1.x += vb.x; a1.y += vb.y;
    }
    if (e < e1) {
        int sa = edge_src[e];
        float2 va = f2[sa * 64 + lane];
        a0.x += va.x; a0.y += va.y;
    }
    float2 o; o.x = a0.x + a1.x; o.y = a0.y + a1.y;
    ((float2*)agg)[node * 64 + lane] = o;
}

// ===========================================================================
// Fused dual GEMM + bias + ReLU:
//   H[n][j] = relu( agg[n,:]·Wrel[j,:] + Ax[n,:]·Wroot[j,:] + b[j] )
// 64 rows x 128 cols per block, 256 threads, 4x8 acc per thread.
// Thread cols: {tx*4..tx*4+3} and {64+tx*4..64+tx*4+3}  (conflict-free b128).
// a_s stored transposed [dd][row] so the A read is one b128 broadcast.
// POOL epilogue: accumulate relu(h2) directly into per-graph sums (batch is
// sorted -> run-compress the thread's 4 rows, ~8 atomics per thread).
// ===========================================================================
template <bool POOL>
__global__ __launch_bounds__(256)
void gemm_kernel(const float* __restrict__ Aagg, const float* __restrict__ Ax,
                 const float* __restrict__ Wrel, const float* __restrict__ Wroot,
                 const float* __restrict__ bias,
                 float* __restrict__ Hout,      // !POOL
                 float* __restrict__ pooled,    // POOL
                 const int* __restrict__ batch) // POOL
{
    __shared__ __align__(16) float a_s[32][68];    // [dd][row], pad->17 float4
    __shared__ __align__(16) float w_s[32][132];   // [dd][col], pad->33 float4

    const int row0 = blockIdx.x * 64;
    const int t  = threadIdx.x;
    const int tx = t & 15;
    const int ty = t >> 4;

    float acc[4][8];
#pragma unroll
    for (int r = 0; r < 4; ++r)
#pragma unroll
        for (int c = 0; c < 8; ++c) acc[r][c] = 0.f;

    for (int kc = 0; kc < 8; ++kc) {
        const float* Asrc = (kc < 4) ? Aagg : Ax;
        const float* Wm   = (kc < 4) ? Wrel : Wroot;
        const int dbase = (kc & 3) * 32;

        // stage A chunk (64 rows x 32 dd), transposed into a_s[dd][r]
#pragma unroll
        for (int i = 0; i < 8; ++i) {
            int idx = t + i * 256;            // 0..2047
            int r  = idx >> 5;
            int dd = idx & 31;
            int row = row0 + r;
            float v = 0.f;
            if (row < N_NODES) v = Asrc[row * DIM + dbase + dd];
            a_s[dd][r] = v;
        }
        // stage W chunk transposed: w_s[dd][j] = Wm[j][dbase+dd]
#pragma unroll
        for (int i = 0; i < 16; ++i) {
            int idx = t + i * 256;            // 0..4095
            int j  = idx >> 5;
            int dd = idx & 31;
            w_s[dd][j] = Wm[j * DIM + dbase + dd];
        }
        __syncthreads();

        const float4* A4 = (const float4*)&a_s[0][0];  // row stride 17
        const float4* W4 = (const float4*)&w_s[0][0];  // row stride 33
#pragma unroll
        for (int dd = 0; dd < 32; ++dd) {
            float4 a  = A4[dd * 17 + ty];
            float4 w0 = W4[dd * 33 + tx];
            float4 w1 = W4[dd * 33 + 16 + tx];
            float av[4] = {a.x, a.y, a.z, a.w};
            float wv[8] = {w0.x, w0.y, w0.z, w0.w, w1.x, w1.y, w1.z, w1.w};
#pragma unroll
            for (int r = 0; r < 4; ++r)
#pragma unroll
                for (int c = 0; c < 8; ++c)
                    acc[r][c] = fmaf(av[r], wv[c], acc[r][c]);
        }
        __syncthreads();
    }

    // bias for my two column blocks
    float4 bv0 = ((const float4*)bias)[tx];
    float4 bv1 = ((const float4*)bias)[16 + tx];
    float bb[8] = {bv0.x, bv0.y, bv0.z, bv0.w, bv1.x, bv1.y, bv1.z, bv1.w};

    if (!POOL) {
#pragma unroll
        for (int r = 0; r < 4; ++r) {
            int row = row0 + ty * 4 + r;
            if (row < N_NODES) {
                float v[8];
#pragma unroll
                for (int c = 0; c < 8; ++c) {
                    float x = acc[r][c] + bb[c];
                    v[c] = x > 0.f ? x : 0.f;
                }
                float4 o0 = {v[0], v[1], v[2], v[3]};
                float4 o1 = {v[4], v[5], v[6], v[7]};
                *(float4*)&Hout[row * DIM + tx * 4]      = o0;
                *(float4*)&Hout[row * DIM + 64 + tx * 4] = o1;
            }
        }
    } else {
        int gprev = -1;
        float sum[8];
#pragma unroll
        for (int r = 0; r < 4; ++r) {
            int row = row0 + ty * 4 + r;
            if (row >= N_NODES) break;
            int g = batch[row];
            float v[8];
#pragma unroll
            for (int c = 0; c < 8; ++c) {
                float x = acc[r][c] + bb[c];
                v[c] = x > 0.f ? x : 0.f;
            }
            if (g != gprev) {
                if (gprev >= 0) {
#pragma unroll
                    for (int c = 0; c < 4; ++c) {
                        atomicAdd(&pooled[gprev * DIM + tx * 4 + c],      sum[c]);
                        atomicAdd(&pooled[gprev * DIM + 64 + tx * 4 + c], sum[4 + c]);
                    }
                }
#pragma unroll
                for (int c = 0; c < 8; ++c) sum[c] = v[c];
                gprev = g;
            } else {
#pragma unroll
                for (int c = 0; c < 8; ++c) sum[c] += v[c];
            }
        }
        if (gprev >= 0) {
#pragma unroll
            for (int c = 0; c < 4; ++c) {
                atomicAdd(&pooled[gprev * DIM + tx * 4 + c],      sum[c]);
                atomicAdd(&pooled[gprev * DIM + 64 + tx * 4 + c], sum[4 + c]);
            }
        }
    }
}

// ===========================================================================
// out[g] = (pooled_sum[g]·W_out) / max(cnt_g,1) + b_out.
// cnt_g from binary search over the sorted batch array (wave-uniform).
// ===========================================================================
__global__ void finalize_kernel(const float* __restrict__ pooled, const int* __restrict__ batch,
                                const float* __restrict__ Wout, const float* __restrict__ bout,
                                float* __restrict__ out)
{
    int g = blockIdx.x;
    int lane = threadIdx.x;  // 0..63

    // lower_bound(g) / lower_bound(g+1) over sorted batch
    int lo0 = 0, hi0 = N_NODES;
    while (lo0 < hi0) { int m = (lo0 + hi0) >> 1; if (batch[m] < g) lo0 = m + 1; else hi0 = m; }
    int lo1 = lo0, hi1 = N_NODES;
    while (lo1 < hi1) { int m = (lo1 + hi1) >> 1; if (batch[m] < g + 1) lo1 = m + 1; else hi1 = m; }
    int cnt = lo1 - lo0;

    float s = pooled[g * DIM + lane]      * Wout[lane]
            + pooled[g * DIM + 64 + lane] * Wout[64 + lane];
#pragma unroll
    for (int off = 32; off > 0; off >>= 1) s += __shfl_xor(s, off, 64);
    if (lane == 0) {
        float c = (float)(cnt > 1 ? cnt : 1);
        out[g] = s / c + bout[0];
    }
}

extern "C" void kernel_launch(void* const* d_in, const int* in_sizes, int n_in,
                              void* d_out, int out_size, void* d_ws, size_t ws_size,
                              hipStream_t stream)
{
    const float* x       = (const float*)d_in[0];
    const int*   ei      = (const int*)d_in[1];   // [2][E]: row 0 = src, row 1 = dst
    const int*   batch   = (const int*)d_in[2];
    const float* W1_rel  = (const float*)d_in[3];
    const float* W1_root = (const float*)d_in[4];
    const float* b1      = (const float*)d_in[5];
    const float* W2_rel  = (const float*)d_in[6];
    const float* W2_root = (const float*)d_in[7];
    const float* b2      = (const float*)d_in[8];
    const float* W_out   = (const float*)d_in[9];
    const float* b_out   = (const float*)d_in[10];
    float* out = (float*)d_out;

    const int* src  = ei;
    const int* dstv = ei + N_EDGES;

    // Workspace layout (bytes):
    //   agg      @ 0          : 25,600,000  (f32, reused both layers)
    //   h1       @ 25,600,000 : 25,600,000  (f32 layer-1 activations)
    //   pooled   @ 51,200,000 :    131,072
    //   deg/cur  @ 51,331,072 :    200,000
    //   row_ptr  @ 51,531,072 :    200,004
    //   edge_src @ 51,731,200 :  2,000,000   (total ~53.7 MB)
    char* ws = (char*)d_ws;
    float* agg      = (float*)ws;
    float* h1       = (float*)(ws + 25600000);
    float* pooled   = (float*)(ws + 51200000);
    int*   deg      = (int*)  (ws + 51331072);   // becomes cursor after scan
    int*   row_ptr  = (int*)  (ws + 51531072);
    int*   edge_src = (int*)  (ws + 51731200);

    // ---- CSR build (once; shared by both layers) ----
    hipMemsetAsync(deg, 0, N_NODES * sizeof(int), stream);
    hipMemsetAsync(pooled, 0, N_GRAPHS * DIM * sizeof(float), stream);
    hist_kernel <<<(N_EDGES + 255) / 256, 256, 0, stream>>>(dstv, deg);
    scan_kernel <<<1, 1024, 0, stream>>>(deg, row_ptr);
    build_kernel<<<(N_EDGES + 255) / 256, 256, 0, stream>>>(src, dstv, deg, edge_src);

    // ---- Layer 1 ----
    gather_kernel<<<N_NODES / 4, 256, 0, stream>>>(x, row_ptr, edge_src, agg);
    gemm_kernel<false><<<(N_NODES + 63) / 64, 256, 0, stream>>>(
        agg, x, W1_rel, W1_root, b1, h1, nullptr, nullptr);

    // ---- Layer 2 (+ fused mean-pool numerator) ----
    gather_kernel<<<N_NODES / 4, 256, 0, stream>>>(h1, row_ptr, edge_src, agg);
    gemm_kernel<true><<<(N_NODES + 63) / 64, 256, 0, stream>>>(
        agg, h1, W2_rel, W2_root, b2, nullptr, pooled, batch);

    // ---- Output head ----
    finalize_kernel<<<N_GRAPHS, 64, 0, stream>>>(pooled, batch, W_out, b_out, out);
}

// Round 4
// 370.903 us; speedup vs baseline: 2.3783x; 1.3056x over previous
//
#include <hip/hip_runtime.h>

#define N_NODES  50000
#define N_EDGES  500000
#define DIM      128
#define N_GRAPHS 256

#define SCAN_B   512
#define SCAN_NB  ((N_NODES + SCAN_B - 1) / SCAN_B)   // 98

// ===========================================================================
// CSR build (edge list identical for both layers -> build once per call)
// ===========================================================================
__global__ void hist_kernel(const int* __restrict__ dst, int* __restrict__ deg)
{
    int e = blockIdx.x * blockDim.x + threadIdx.x;
    if (e < N_EDGES) atomicAdd(&deg[dst[e]], 1);
}

// ---- device-wide exclusive scan of deg[50000], 3 tiny parallel phases ----
__global__ __launch_bounds__(SCAN_B)
void block_sum_kernel(const int* __restrict__ deg, int* __restrict__ bsum)
{
    __shared__ int red[SCAN_B];
    int t = threadIdx.x;
    int idx = blockIdx.x * SCAN_B + t;
    red[t] = (idx < N_NODES) ? deg[idx] : 0;
    __syncthreads();
    for (int off = SCAN_B / 2; off > 0; off >>= 1) {
        if (t < off) red[t] += red[t + off];
        __syncthreads();
    }
    if (t == 0) bsum[blockIdx.x] = red[0];
}

__global__ __launch_bounds__(128)
void scan_sums_kernel(int* __restrict__ bsum)   // in-place -> exclusive prefix
{
    __shared__ int s[128];
    int t = threadIdx.x;
    int v = (t < SCAN_NB) ? bsum[t] : 0;
    s[t] = v;
    __syncthreads();
    for (int off = 1; off < 128; off <<= 1) {
        int u = (t >= off) ? s[t - off] : 0;
        __syncthreads();
        s[t] += u;
        __syncthreads();
    }
    if (t < SCAN_NB) bsum[t] = s[t] - v;        // exclusive
}

__global__ __launch_bounds__(SCAN_B)
void scan_apply_kernel(const int* __restrict__ deg, const int* __restrict__ bsum,
                       int* __restrict__ row_ptr, int* __restrict__ cursor)
{
    __shared__ int s[SCAN_B];
    int t = threadIdx.x;
    int idx = blockIdx.x * SCAN_B + t;
    int v = (idx < N_NODES) ? deg[idx] : 0;
    s[t] = v;
    __syncthreads();
    for (int off = 1; off < SCAN_B; off <<= 1) {   // Hillis-Steele inclusive
        int u = (t >= off) ? s[t - off] : 0;
        __syncthreads();
        s[t] += u;
        __syncthreads();
    }
    if (idx < N_NODES) {
        int ex = bsum[blockIdx.x] + s[t] - v;       // exclusive global prefix
        row_ptr[idx] = ex;
        cursor[idx]  = ex;
    }
    if (idx == 0) row_ptr[N_NODES] = N_EDGES;       // every dst is in range
}

__global__ void build_kernel(const int* __restrict__ src, const int* __restrict__ dst,
                             int* __restrict__ cursor, int* __restrict__ edge_src)
{
    int e = blockIdx.x * blockDim.x + threadIdx.x;
    if (e < N_EDGES) {
        int pos = atomicAdd(&cursor[dst[e]], 1);
        edge_src[pos] = src[e];
    }
}

// ===========================================================================
// Gather-aggregate: one wave per node, lane holds 2 features (float2).
// agg[n][:] = sum over in-edges of feat[src][:]   -- no atomics, no memset.
// ===========================================================================
__global__ __launch_bounds__(256)
void gather_kernel(const float* __restrict__ feat,
                   const int* __restrict__ row_ptr,
                   const int* __restrict__ edge_src,
                   float* __restrict__ agg)
{
    int wid  = (blockIdx.x * blockDim.x + threadIdx.x) >> 6;
    int lane = threadIdx.x & 63;
    int node = __builtin_amdgcn_readfirstlane(wid);   // wave-uniform -> SGPR

    const float2* f2 = (const float2*)feat;
    int e  = row_ptr[node];
    int e1 = row_ptr[node + 1];

    float2 a0 = make_float2(0.f, 0.f), a1 = make_float2(0.f, 0.f);
    for (; e + 1 < e1; e += 2) {                      // 2x unroll for load ILP
        int sa = edge_src[e], sb = edge_src[e + 1];   // wave-uniform scalar loads
        float2 va = f2[sa * 64 + lane];
        float2 vb = f2[sb * 64 + lane];
        a0.x += va.x; a0.y += va.y;
        a1.x += vb.x; a1.y += vb.y;
    }
    if (e < e1) {
        int sa = edge_src[e];
        float2 va = f2[sa * 64 + lane];
        a0.x += va.x; a0.y += va.y;
    }
    float2 o; o.x = a0.x + a1.x; o.y = a0.y + a1.y;
    ((float2*)agg)[node * 64 + lane] = o;
}

// ===========================================================================
// Fused dual GEMM + bias + ReLU:
//   H[n][j] = relu( agg[n,:]·Wrel[j,:] + Ax[n,:]·Wroot[j,:] + b[j] )
// 64 rows x 128 cols per block, 256 threads, 4x8 acc per thread.
// POOL epilogue: accumulate relu(h2) into per-graph sums (batch sorted ->
// run-compress the thread's 4 rows, ~8 atomics per thread).
// ===========================================================================
template <bool POOL>
__global__ __launch_bounds__(256)
void gemm_kernel(const float* __restrict__ Aagg, const float* __restrict__ Ax,
                 const float* __restrict__ Wrel, const float* __restrict__ Wroot,
                 const float* __restrict__ bias,
                 float* __restrict__ Hout,      // !POOL
                 float* __restrict__ pooled,    // POOL
                 const int* __restrict__ batch) // POOL
{
    __shared__ __align__(16) float a_s[32][68];    // [dd][row], pad->17 float4
    __shared__ __align__(16) float w_s[32][132];   // [dd][col], pad->33 float4

    const int row0 = blockIdx.x * 64;
    const int t  = threadIdx.x;
    const int tx = t & 15;
    const int ty = t >> 4;

    float acc[4][8];
#pragma unroll
    for (int r = 0; r < 4; ++r)
#pragma unroll
        for (int c = 0; c < 8; ++c) acc[r][c] = 0.f;

    for (int kc = 0; kc < 8; ++kc) {
        const float* Asrc = (kc < 4) ? Aagg : Ax;
        const float* Wm   = (kc < 4) ? Wrel : Wroot;
        const int dbase = (kc & 3) * 32;

        // stage A chunk (64 rows x 32 dd), transposed into a_s[dd][r]
#pragma unroll
        for (int i = 0; i < 8; ++i) {
            int idx = t + i * 256;            // 0..2047
            int r  = idx >> 5;
            int dd = idx & 31;
            int row = row0 + r;
            float v = 0.f;
            if (row < N_NODES) v = Asrc[row * DIM + dbase + dd];
            a_s[dd][r] = v;
        }
        // stage W chunk transposed: w_s[dd][j] = Wm[j][dbase+dd]
#pragma unroll
        for (int i = 0; i < 16; ++i) {
            int idx = t + i * 256;            // 0..4095
            int j  = idx >> 5;
            int dd = idx & 31;
            w_s[dd][j] = Wm[j * DIM + dbase + dd];
        }
        __syncthreads();

        const float4* A4 = (const float4*)&a_s[0][0];  // row stride 17
        const float4* W4 = (const float4*)&w_s[0][0];  // row stride 33
#pragma unroll
        for (int dd = 0; dd < 32; ++dd) {
            float4 a  = A4[dd * 17 + ty];
            float4 w0 = W4[dd * 33 + tx];
            float4 w1 = W4[dd * 33 + 16 + tx];
            float av[4] = {a.x, a.y, a.z, a.w};
            float wv[8] = {w0.x, w0.y, w0.z, w0.w, w1.x, w1.y, w1.z, w1.w};
#pragma unroll
            for (int r = 0; r < 4; ++r)
#pragma unroll
                for (int c = 0; c < 8; ++c)
                    acc[r][c] = fmaf(av[r], wv[c], acc[r][c]);
        }
        __syncthreads();
    }

    // bias for my two column blocks
    float4 bv0 = ((const float4*)bias)[tx];
    float4 bv1 = ((const float4*)bias)[16 + tx];
    float bb[8] = {bv0.x, bv0.y, bv0.z, bv0.w, bv1.x, bv1.y, bv1.z, bv1.w};

    if (!POOL) {
#pragma unroll
        for (int r = 0; r < 4; ++r) {
            int row = row0 + ty * 4 + r;
            if (row < N_NODES) {
                float v[8];
#pragma unroll
                for (int c = 0; c < 8; ++c) {
                    float x = acc[r][c] + bb[c];
                    v[c] = x > 0.f ? x : 0.f;
                }
                float4 o0 = {v[0], v[1], v[2], v[3]};
                float4 o1 = {v[4], v[5], v[6], v[7]};
                *(float4*)&Hout[row * DIM + tx * 4]      = o0;
                *(float4*)&Hout[row * DIM + 64 + tx * 4] = o1;
            }
        }
    } else {
        int gprev = -1;
        float sum[8];
#pragma unroll
        for (int r = 0; r < 4; ++r) {
            int row = row0 + ty * 4 + r;
            if (row >= N_NODES) break;
            int g = batch[row];
            float v[8];
#pragma unroll
            for (int c = 0; c < 8; ++c) {
                float x = acc[r][c] + bb[c];
                v[c] = x > 0.f ? x : 0.f;
            }
            if (g != gprev) {
                if (gprev >= 0) {
#pragma unroll
                    for (int c = 0; c < 4; ++c) {
                        atomicAdd(&pooled[gprev * DIM + tx * 4 + c],      sum[c]);
                        atomicAdd(&pooled[gprev * DIM + 64 + tx * 4 + c], sum[4 + c]);
                    }
                }
#pragma unroll
                for (int c = 0; c < 8; ++c) sum[c] = v[c];
                gprev = g;
            } else {
#pragma unroll
                for (int c = 0; c < 8; ++c) sum[c] += v[c];
            }
        }
        if (gprev >= 0) {
#pragma unroll
            for (int c = 0; c < 4; ++c) {
                atomicAdd(&pooled[gprev * DIM + tx * 4 + c],      sum[c]);
                atomicAdd(&pooled[gprev * DIM + 64 + tx * 4 + c], sum[4 + c]);
            }
        }
    }
}

// ===========================================================================
// out[g] = (pooled_sum[g]·W_out) / max(cnt_g,1) + b_out.
// cnt_g from binary search over the sorted batch array (wave-uniform).
// ===========================================================================
__global__ void finalize_kernel(const float* __restrict__ pooled, const int* __restrict__ batch,
                                const float* __restrict__ Wout, const float* __restrict__ bout,
                                float* __restrict__ out)
{
    int g = blockIdx.x;
    int lane = threadIdx.x;  // 0..63

    int lo0 = 0, hi0 = N_NODES;
    while (lo0 < hi0) { int m = (lo0 + hi0) >> 1; if (batch[m] < g) lo0 = m + 1; else hi0 = m; }
    int lo1 = lo0, hi1 = N_NODES;
    while (lo1 < hi1) { int m = (lo1 + hi1) >> 1; if (batch[m] < g + 1) lo1 = m + 1; else hi1 = m; }
    int cnt = lo1 - lo0;

    float s = pooled[g * DIM + lane]      * Wout[lane]
            + pooled[g * DIM + 64 + lane] * Wout[64 + lane];
#pragma unroll
    for (int off = 32; off > 0; off >>= 1) s += __shfl_xor(s, off, 64);
    if (lane == 0) {
        float c = (float)(cnt > 1 ? cnt : 1);
        out[g] = s / c + bout[0];
    }
}

extern "C" void kernel_launch(void* const* d_in, const int* in_sizes, int n_in,
                              void* d_out, int out_size, void* d_ws, size_t ws_size,
                              hipStream_t stream)
{
    const float* x       = (const float*)d_in[0];
    const int*   ei      = (const int*)d_in[1];   // [2][E]: row 0 = src, row 1 = dst
    const int*   batch   = (const int*)d_in[2];
    const float* W1_rel  = (const float*)d_in[3];
    const float* W1_root = (const float*)d_in[4];
    const float* b1      = (const float*)d_in[5];
    const float* W2_rel  = (const float*)d_in[6];
    const float* W2_root = (const float*)d_in[7];
    const float* b2      = (const float*)d_in[8];
    const float* W_out   = (const float*)d_in[9];
    const float* b_out   = (const float*)d_in[10];
    float* out = (float*)d_out;

    const int* src  = ei;
    const int* dstv = ei + N_EDGES;

    // Workspace layout (bytes):
    //   agg      @ 0          : 25,600,000  (f32, reused both layers)
    //   h1       @ 25,600,000 : 25,600,000  (f32 layer-1 activations)
    //   pooled   @ 51,200,000 :    131,072
    //   deg      @ 51,331,072 :    200,000
    //   row_ptr  @ 51,531,072 :    200,004
    //   edge_src @ 51,731,200 :  2,000,000
    //   cursor   @ 53,731,200 :    200,000
    //   bsum     @ 53,931,200 :        512   (total ~53.9 MB)
    char* ws = (char*)d_ws;
    float* agg      = (float*)ws;
    float* h1       = (float*)(ws + 25600000);
    float* pooled   = (float*)(ws + 51200000);
    int*   deg      = (int*)  (ws + 51331072);
    int*   row_ptr  = (int*)  (ws + 51531072);
    int*   edge_src = (int*)  (ws + 51731200);
    int*   cursor   = (int*)  (ws + 53731200);
    int*   bsum     = (int*)  (ws + 53931200);

    // ---- CSR build (once; shared by both layers) ----
    hipMemsetAsync(deg, 0, N_NODES * sizeof(int), stream);
    hipMemsetAsync(pooled, 0, N_GRAPHS * DIM * sizeof(float), stream);
    hist_kernel      <<<(N_EDGES + 255) / 256, 256, 0, stream>>>(dstv, deg);
    block_sum_kernel <<<SCAN_NB, SCAN_B, 0, stream>>>(deg, bsum);
    scan_sums_kernel <<<1, 128, 0, stream>>>(bsum);
    scan_apply_kernel<<<SCAN_NB, SCAN_B, 0, stream>>>(deg, bsum, row_ptr, cursor);
    build_kernel     <<<(N_EDGES + 255) / 256, 256, 0, stream>>>(src, dstv, cursor, edge_src);

    // ---- Layer 1 ----
    gather_kernel<<<N_NODES / 4, 256, 0, stream>>>(x, row_ptr, edge_src, agg);
    gemm_kernel<false><<<(N_NODES + 63) / 64, 256, 0, stream>>>(
        agg, x, W1_rel, W1_root, b1, h1, nullptr, nullptr);

    // ---- Layer 2 (+ fused mean-pool numerator) ----
    gather_kernel<<<N_NODES / 4, 256, 0, stream>>>(h1, row_ptr, edge_src, agg);
    gemm_kernel<true><<<(N_NODES + 63) / 64, 256, 0, stream>>>(
        agg, h1, W2_rel, W2_root, b2, nullptr, pooled, batch);

    // ---- Output head ----
    finalize_kernel<<<N_GRAPHS, 64, 0, stream>>>(pooled, batch, W_out, b_out, out);
}

// Round 6
// 275.493 us; speedup vs baseline: 3.2020x; 1.3463x over previous
//
#include <hip/hip_runtime.h>
#include <hip/hip_bf16.h>

#define N_NODES  50000
#define N_EDGES  500000
#define DIM      128
#define N_GRAPHS 256

#define SCAN_B   512
#define SCAN_NB  ((N_NODES + SCAN_B - 1) / SCAN_B)   // 98

#define WSTRIDE  264   // bf16 units per wlds row: 16B-aligned, even 8-phase bank spread

typedef __attribute__((ext_vector_type(8))) short bf16x8;
typedef __attribute__((ext_vector_type(4))) float f32x4;

__device__ __forceinline__ unsigned short f2bf(float f) {
    __hip_bfloat16 h = __float2bfloat16(f);          // RNE
    return *(unsigned short*)&h;
}
__device__ __forceinline__ float bflo(unsigned int v) {        // low bf16 -> f32
    unsigned int u = v << 16; return __uint_as_float(u);
}
__device__ __forceinline__ float bfhi(unsigned int v) {        // high bf16 -> f32
    unsigned int u = v & 0xffff0000u; return __uint_as_float(u);
}

// ===========================================================================
// x (f32) -> bf16, one float4 per thread.
// ===========================================================================
__global__ void cvt_kernel(const float* __restrict__ in, unsigned short* __restrict__ out)
{
    int i = blockIdx.x * blockDim.x + threadIdx.x;   // < N_NODES*DIM/4 exactly
    float4 v = ((const float4*)in)[i];
    ushort4 o;
    o.x = f2bf(v.x); o.y = f2bf(v.y); o.z = f2bf(v.z); o.w = f2bf(v.w);
    ((ushort4*)out)[i] = o;
}

// ===========================================================================
// CSR build (edge list identical for both layers -> build once per call)
// ===========================================================================
__global__ void hist_kernel(const int* __restrict__ dst, int* __restrict__ deg)
{
    int e = blockIdx.x * blockDim.x + threadIdx.x;
    if (e < N_EDGES) atomicAdd(&deg[dst[e]], 1);
}

__global__ __launch_bounds__(SCAN_B)
void block_sum_kernel(const int* __restrict__ deg, int* __restrict__ bsum)
{
    __shared__ int red[SCAN_B];
    int t = threadIdx.x;
    int idx = blockIdx.x * SCAN_B + t;
    red[t] = (idx < N_NODES) ? deg[idx] : 0;
    __syncthreads();
    for (int off = SCAN_B / 2; off > 0; off >>= 1) {
        if (t < off) red[t] += red[t + off];
        __syncthreads();
    }
    if (t == 0) bsum[blockIdx.x] = red[0];
}

__global__ __launch_bounds__(128)
void scan_sums_kernel(int* __restrict__ bsum)   // in-place -> exclusive prefix
{
    __shared__ int s[128];
    int t = threadIdx.x;
    int v = (t < SCAN_NB) ? bsum[t] : 0;
    s[t] = v;
    __syncthreads();
    for (int off = 1; off < 128; off <<= 1) {
        int u = (t >= off) ? s[t - off] : 0;
        __syncthreads();
        s[t] += u;
        __syncthreads();
    }
    if (t < SCAN_NB) bsum[t] = s[t] - v;
}

__global__ __launch_bounds__(SCAN_B)
void scan_apply_kernel(const int* __restrict__ deg, const int* __restrict__ bsum,
                       int* __restrict__ row_ptr, int* __restrict__ cursor)
{
    __shared__ int s[SCAN_B];
    int t = threadIdx.x;
    int idx = blockIdx.x * SCAN_B + t;
    int v = (idx < N_NODES) ? deg[idx] : 0;
    s[t] = v;
    __syncthreads();
    for (int off = 1; off < SCAN_B; off <<= 1) {
        int u = (t >= off) ? s[t - off] : 0;
        __syncthreads();
        s[t] += u;
        __syncthreads();
    }
    if (idx < N_NODES) {
        int ex = bsum[blockIdx.x] + s[t] - v;
        row_ptr[idx] = ex;
        cursor[idx]  = ex;
    }
    if (idx == 0) row_ptr[N_NODES] = N_EDGES;
}

__global__ void build_kernel(const int* __restrict__ src, const int* __restrict__ dst,
                             int* __restrict__ cursor, int* __restrict__ edge_src)
{
    int e = blockIdx.x * blockDim.x + threadIdx.x;
    if (e < N_EDGES) {
        int pos = atomicAdd(&cursor[dst[e]], 1);
        edge_src[pos] = src[e];
    }
}

// ===========================================================================
// Gather-aggregate (bf16 feat -> bf16 agg, f32 accumulate in-register).
// One wave per node; lane holds 2 features packed in one uint.
// ===========================================================================
__global__ __launch_bounds__(256)
void gather_kernel(const unsigned short* __restrict__ feat,
                   const int* __restrict__ row_ptr,
                   const int* __restrict__ edge_src,
                   unsigned short* __restrict__ agg)
{
    int wid  = (blockIdx.x * blockDim.x + threadIdx.x) >> 6;
    int lane = threadIdx.x & 63;
    int node = __builtin_amdgcn_readfirstlane(wid);

    const unsigned int* f = (const unsigned int*)feat;   // 2 bf16 per uint
    int e  = row_ptr[node];
    int e1 = row_ptr[node + 1];

    float a0 = 0.f, a1 = 0.f, b0 = 0.f, b1 = 0.f;
    for (; e + 1 < e1; e += 2) {
        int sa = edge_src[e], sb = edge_src[e + 1];      // wave-uniform
        unsigned int va = f[sa * 64 + lane];
        unsigned int vb = f[sb * 64 + lane];
        a0 += bflo(va); a1 += bfhi(va);
        b0 += bflo(vb); b1 += bfhi(vb);
    }
    if (e < e1) {
        unsigned int va = f[edge_src[e] * 64 + lane];
        a0 += bflo(va); a1 += bfhi(va);
    }
    unsigned int o = (unsigned int)f2bf(a0 + b0) | ((unsigned int)f2bf(a1 + b1) << 16);
    ((unsigned int*)agg)[node * 64 + lane] = o;
}

// ===========================================================================
// MFMA GEMM:  H[n][j] = relu( [agg|x][n,0:256] . Wcomb[j,0:256] + b[j] )
// Block = 256 thr = 4 waves; wave owns 16 rows x 128 cols (8 16x16 tiles).
// W (both matrices, f32 global) staged ONCE to LDS as bf16 [col][0:256],
// row stride 264 (16B-aligned, even bank spread). Barrier-free K-loop.
// A-frags loaded directly from global (8 contiguous bf16 = dwordx4).
// POOL: fused mean-pool numerator via run-compressed atomics (batch sorted;
// C-layout gives each lane 4 consecutive rows).
// ===========================================================================
template <bool POOL>
__global__ __launch_bounds__(256)
void gemm_mfma(const unsigned short* __restrict__ Aagg,
               const unsigned short* __restrict__ Ax,
               const float* __restrict__ Wrel, const float* __restrict__ Wroot,
               const float* __restrict__ bias,
               unsigned short* __restrict__ Hout,   // !POOL
               float* __restrict__ pooled,          // POOL
               const int* __restrict__ batch)       // POOL
{
    __shared__ __align__(16) unsigned short wlds[128][WSTRIDE];  // [col][k 0..255]

    const int t = threadIdx.x;

    // ---- stage W once: thread pair per col; (t&1)==0 -> Wrel (k 0..127), ==1 -> Wroot (k 128..255) ----
    {
        int col = t >> 1;
        const float* Wm = (t & 1) ? Wroot : Wrel;
        const float4* w4 = (const float4*)(Wm + col * 128);
        unsigned short* dstp = &wlds[col][(t & 1) * 128];
#pragma unroll
        for (int i = 0; i < 32; ++i) {
            float4 v = w4[i];
            ushort4 o;
            o.x = f2bf(v.x); o.y = f2bf(v.y); o.z = f2bf(v.z); o.w = f2bf(v.w);
            *(ushort4*)&dstp[i * 4] = o;
        }
    }
    __syncthreads();

    const int wave = t >> 6;
    const int lane = t & 63;
    const int q    = lane >> 4;                 // 0..3
    const int ln15 = lane & 15;
    const int m0   = blockIdx.x * 64 + wave * 16;
    int arow = m0 + ln15;
    int rowc = arow < N_NODES ? arow : N_NODES - 1;   // clamp; guarded at store

    const unsigned short* A0 = Aagg + (size_t)rowc * DIM + q * 8;  // k 0..127
    const unsigned short* A1 = Ax   + (size_t)rowc * DIM + q * 8;  // k 128..255

    f32x4 acc[8];
#pragma unroll
    for (int ct = 0; ct < 8; ++ct) acc[ct] = (f32x4){0.f, 0.f, 0.f, 0.f};

#pragma unroll
    for (int ks = 0; ks < 8; ++ks) {
        const unsigned short* ap = (ks < 4) ? (A0 + ks * 32) : (A1 + (ks - 4) * 32);
        bf16x8 afrag = *(const bf16x8*)ap;
        const int k0 = ks * 32;
#pragma unroll
        for (int ct = 0; ct < 8; ++ct) {
            bf16x8 bfrag = *(const bf16x8*)&wlds[ct * 16 + ln15][k0 + q * 8];
            acc[ct] = __builtin_amdgcn_mfma_f32_16x16x32_bf16(afrag, bfrag, acc[ct], 0, 0, 0);
        }
    }

    // bias per col-tile (f32)
    float bj[8];
#pragma unroll
    for (int ct = 0; ct < 8; ++ct) bj[ct] = bias[ct * 16 + ln15];

    const int rb = m0 + q * 4;     // this lane's 4 consecutive rows: rb..rb+3

    if (!POOL) {
#pragma unroll
        for (int ct = 0; ct < 8; ++ct) {
            int coln = ct * 16 + ln15;
#pragma unroll
            for (int r = 0; r < 4; ++r) {
                int row = rb + r;
                if (row < N_NODES) {
                    float v = acc[ct][r] + bj[ct];
                    v = v > 0.f ? v : 0.f;
                    Hout[(size_t)row * DIM + coln] = f2bf(v);
                }
            }
        }
    } else {
        int gg[4];
#pragma unroll
        for (int r = 0; r < 4; ++r) gg[r] = (rb + r < N_NODES) ? batch[rb + r] : -1;
        bool uni = (gg[0] == gg[3]) && (gg[3] >= 0);   // sorted -> all 4 equal
#pragma unroll
        for (int ct = 0; ct < 8; ++ct) {
            int coln = ct * 16 + ln15;
            float v[4];
#pragma unroll
            for (int r = 0; r < 4; ++r) {
                float x = acc[ct][r] + bj[ct];
                v[r] = x > 0.f ? x : 0.f;
            }
            if (uni) {
                atomicAdd(&pooled[gg[0] * DIM + coln], v[0] + v[1] + v[2] + v[3]);
            } else {
#pragma unroll
                for (int r = 0; r < 4; ++r)
                    if (gg[r] >= 0) atomicAdd(&pooled[gg[r] * DIM + coln], v[r]);
            }
        }
    }
}

// ===========================================================================
// out[g] = (pooled_sum[g]·W_out) / max(cnt_g,1) + b_out.  (all f32)
// ===========================================================================
__global__ void finalize_kernel(const float* __restrict__ pooled, const int* __restrict__ batch,
                                const float* __restrict__ Wout, const float* __restrict__ bout,
                                float* __restrict__ out)
{
    int g = blockIdx.x;
    int lane = threadIdx.x;  // 0..63

    int lo0 = 0, hi0 = N_NODES;
    while (lo0 < hi0) { int m = (lo0 + hi0) >> 1; if (batch[m] < g) lo0 = m + 1; else hi0 = m; }
    int lo1 = lo0, hi1 = N_NODES;
    while (lo1 < hi1) { int m = (lo1 + hi1) >> 1; if (batch[m] < g + 1) lo1 = m + 1; else hi1 = m; }
    int cnt = lo1 - lo0;

    float s = pooled[g * DIM + lane]      * Wout[lane]
            + pooled[g * DIM + 64 + lane] * Wout[64 + lane];
#pragma unroll
    for (int off = 32; off > 0; off >>= 1) s += __shfl_xor(s, off, 64);
    if (lane == 0) {
        float c = (float)(cnt > 1 ? cnt : 1);
        out[g] = s / c + bout[0];
    }
}

extern "C" void kernel_launch(void* const* d_in, const int* in_sizes, int n_in,
                              void* d_out, int out_size, void* d_ws, size_t ws_size,
                              hipStream_t stream)
{
    const float* x       = (const float*)d_in[0];
    const int*   ei      = (const int*)d_in[1];   // [2][E]: row 0 = src, row 1 = dst
    const int*   batch   = (const int*)d_in[2];
    const float* W1_rel  = (const float*)d_in[3];
    const float* W1_root = (const float*)d_in[4];
    const float* b1      = (const float*)d_in[5];
    const float* W2_rel  = (const float*)d_in[6];
    const float* W2_root = (const float*)d_in[7];
    const float* b2      = (const float*)d_in[8];
    const float* W_out   = (const float*)d_in[9];
    const float* b_out   = (const float*)d_in[10];
    float* out = (float*)d_out;

    const int* src  = ei;
    const int* dstv = ei + N_EDGES;

    // Workspace layout (bytes):
    //   aggb (bf16) @ 0          : 12,800,000
    //   xb   (bf16) @ 12,800,000 : 12,800,000
    //   h1b  (bf16) @ 25,600,000 : 12,800,000
    //   pooled f32  @ 38,400,000 :    131,072
    //   deg         @ 38,531,072 :    200,000
    //   row_ptr     @ 38,731,072 :    200,004
    //   edge_src    @ 38,931,200 :  2,000,000
    //   cursor      @ 40,931,200 :    200,000
    //   bsum        @ 41,131,200 :        512   (~41.1 MB)
    char* ws = (char*)d_ws;
    unsigned short* aggb = (unsigned short*)ws;
    unsigned short* xb   = (unsigned short*)(ws + 12800000);
    unsigned short* h1b  = (unsigned short*)(ws + 25600000);
    float* pooled        = (float*)(ws + 38400000);
    int*   deg           = (int*)  (ws + 38531072);
    int*   row_ptr       = (int*)  (ws + 38731072);
    int*   edge_src      = (int*)  (ws + 38931200);
    int*   cursor        = (int*)  (ws + 40931200);
    int*   bsum          = (int*)  (ws + 41131200);

    // ---- CSR build + conversions ----
    hipMemsetAsync(deg, 0, N_NODES * sizeof(int), stream);
    hipMemsetAsync(pooled, 0, N_GRAPHS * DIM * sizeof(float), stream);
    cvt_kernel       <<<(N_NODES * DIM / 4) / 256, 256, 0, stream>>>(x, xb);
    hist_kernel      <<<(N_EDGES + 255) / 256, 256, 0, stream>>>(dstv, deg);
    block_sum_kernel <<<SCAN_NB, SCAN_B, 0, stream>>>(deg, bsum);
    scan_sums_kernel <<<1, 128, 0, stream>>>(bsum);
    scan_apply_kernel<<<SCAN_NB, SCAN_B, 0, stream>>>(deg, bsum, row_ptr, cursor);
    build_kernel     <<<(N_EDGES + 255) / 256, 256, 0, stream>>>(src, dstv, cursor, edge_src);

    const int gemm_grid = (N_NODES + 63) / 64;   // 782

    // ---- Layer 1 ----
    gather_kernel<<<N_NODES / 4, 256, 0, stream>>>(xb, row_ptr, edge_src, aggb);
    gemm_mfma<false><<<gemm_grid, 256, 0, stream>>>(
        aggb, xb, W1_rel, W1_root, b1, h1b, nullptr, nullptr);

    // ---- Layer 2 (+ fused mean-pool numerator) ----
    gather_kernel<<<N_NODES / 4, 256, 0, stream>>>(h1b, row_ptr, edge_src, aggb);
    gemm_mfma<true><<<gemm_grid, 256, 0, stream>>>(
        aggb, h1b, W2_rel, W2_root, b2, nullptr, pooled, batch);

    // ---- Output head ----
    finalize_kernel<<<N_GRAPHS, 64, 0, stream>>>(pooled, batch, W_out, b_out, out);
}

// Round 7
// 243.490 us; speedup vs baseline: 3.6228x; 1.1314x over previous
//
#include <hip/hip_runtime.h>
#include <hip/hip_bf16.h>

#define N_NODES  50000
#define N_EDGES  500000
#define DIM      128
#define N_GRAPHS 256

#define SCAN_B   512
#define SCAN_NB  ((N_NODES + SCAN_B - 1) / SCAN_B)   // 98

typedef __attribute__((ext_vector_type(8))) short bf16x8;
typedef __attribute__((ext_vector_type(4))) float f32x4;

__device__ __forceinline__ unsigned short f2bf(float f) {
    __hip_bfloat16 h = __float2bfloat16(f);          // RNE
    return *(unsigned short*)&h;
}
__device__ __forceinline__ float bflo(unsigned int v) { return __uint_as_float(v << 16); }
__device__ __forceinline__ float bfhi(unsigned int v) { return __uint_as_float(v & 0xffff0000u); }

// ===========================================================================
// x (f32) -> bf16, one float4 per thread.
// ===========================================================================
__global__ void cvt_kernel(const float* __restrict__ in, unsigned short* __restrict__ out)
{
    int i = blockIdx.x * blockDim.x + threadIdx.x;   // covers N_NODES*DIM/4 exactly
    float4 v = ((const float4*)in)[i];
    ushort4 o;
    o.x = f2bf(v.x); o.y = f2bf(v.y); o.z = f2bf(v.z); o.w = f2bf(v.w);
    ((ushort4*)out)[i] = o;
}

// ===========================================================================
// Weights (f32) -> packed bf16 fragment order: Wb[layer][kb][col][8],
// kb = k/8 (k 0..127 = W_rel, 128..255 = W_root), col = output channel.
// This is byte-for-byte the LDS image the gemm stages (straight memcpy).
// 8192 threads: layer(1b) | kb(5b) | col(7b). Writes coalesced (16B/thread).
// ===========================================================================
__global__ __launch_bounds__(256)
void wcvt_kernel(const float* __restrict__ W1_rel, const float* __restrict__ W1_root,
                 const float* __restrict__ W2_rel, const float* __restrict__ W2_root,
                 unsigned short* __restrict__ Wb)
{
    int u = blockIdx.x * blockDim.x + threadIdx.x;   // 0..8191
    int layer = u >> 12;
    int kb    = (u >> 7) & 31;
    int col   = u & 127;
    int k0    = kb * 8;
    const float* Wrel  = layer ? W2_rel  : W1_rel;
    const float* Wroot = layer ? W2_root : W1_root;
    const float* srcp = (k0 < 128) ? (Wrel + col * 128 + k0) : (Wroot + col * 128 + (k0 - 128));
    float4 v0 = ((const float4*)srcp)[0];
    float4 v1 = ((const float4*)srcp)[1];
    ushort4 o0, o1;
    o0.x = f2bf(v0.x); o0.y = f2bf(v0.y); o0.z = f2bf(v0.z); o0.w = f2bf(v0.w);
    o1.x = f2bf(v1.x); o1.y = f2bf(v1.y); o1.z = f2bf(v1.z); o1.w = f2bf(v1.w);
    unsigned short* dst = Wb + (size_t)layer * 32768 + ((kb * 128 + col) * 8);
    ((ushort4*)dst)[0] = o0;
    ((ushort4*)dst)[1] = o1;
}

// ===========================================================================
// CSR build (edge list identical for both layers -> build once per call)
// ===========================================================================
__global__ void hist_kernel(const int* __restrict__ dst, int* __restrict__ deg)
{
    int e = blockIdx.x * blockDim.x + threadIdx.x;
    if (e < N_EDGES) atomicAdd(&deg[dst[e]], 1);
}

__global__ __launch_bounds__(SCAN_B)
void block_sum_kernel(const int* __restrict__ deg, int* __restrict__ bsum)
{
    __shared__ int red[SCAN_B];
    int t = threadIdx.x;
    int idx = blockIdx.x * SCAN_B + t;
    red[t] = (idx < N_NODES) ? deg[idx] : 0;
    __syncthreads();
    for (int off = SCAN_B / 2; off > 0; off >>= 1) {
        if (t < off) red[t] += red[t + off];
        __syncthreads();
    }
    if (t == 0) bsum[blockIdx.x] = red[0];
}

__global__ __launch_bounds__(128)
void scan_sums_kernel(int* __restrict__ bsum)   // in-place -> exclusive prefix
{
    __shared__ int s[128];
    int t = threadIdx.x;
    int v = (t < SCAN_NB) ? bsum[t] : 0;
    s[t] = v;
    __syncthreads();
    for (int off = 1; off < 128; off <<= 1) {
        int u = (t >= off) ? s[t - off] : 0;
        __syncthreads();
        s[t] += u;
        __syncthreads();
    }
    if (t < SCAN_NB) bsum[t] = s[t] - v;
}

__global__ __launch_bounds__(SCAN_B)
void scan_apply_kernel(const int* __restrict__ deg, const int* __restrict__ bsum,
                       int* __restrict__ row_ptr, int* __restrict__ cursor)
{
    __shared__ int s[SCAN_B];
    int t = threadIdx.x;
    int idx = blockIdx.x * SCAN_B + t;
    int v = (idx < N_NODES) ? deg[idx] : 0;
    s[t] = v;
    __syncthreads();
    for (int off = 1; off < SCAN_B; off <<= 1) {
        int u = (t >= off) ? s[t - off] : 0;
        __syncthreads();
        s[t] += u;
        __syncthreads();
    }
    if (idx < N_NODES) {
        int ex = bsum[blockIdx.x] + s[t] - v;
        row_ptr[idx] = ex;
        cursor[idx]  = ex;
    }
    if (idx == 0) row_ptr[N_NODES] = N_EDGES;
}

__global__ void build_kernel(const int* __restrict__ src, const int* __restrict__ dst,
                             int* __restrict__ cursor, int* __restrict__ edge_src)
{
    int e = blockIdx.x * blockDim.x + threadIdx.x;
    if (e < N_EDGES) {
        int pos = atomicAdd(&cursor[dst[e]], 1);
        edge_src[pos] = src[e];
    }
}

// ===========================================================================
// Gather-aggregate (bf16 feat -> bf16 agg, f32 accumulate in-register).
// One wave per node; lane holds 2 features packed in one uint. 4x unroll
// for 4 outstanding row loads (latency-bound on L2/L3 gathers).
// ===========================================================================
__global__ __launch_bounds__(256)
void gather_kernel(const unsigned short* __restrict__ feat,
                   const int* __restrict__ row_ptr,
                   const int* __restrict__ edge_src,
                   unsigned short* __restrict__ agg)
{
    int wid  = (blockIdx.x * blockDim.x + threadIdx.x) >> 6;
    int lane = threadIdx.x & 63;
    int node = __builtin_amdgcn_readfirstlane(wid);

    const unsigned int* f = (const unsigned int*)feat;   // 2 bf16 per uint
    int e  = row_ptr[node];
    int e1 = row_ptr[node + 1];

    float s0 = 0.f, s1 = 0.f, t0 = 0.f, t1 = 0.f;
    float u0 = 0.f, u1 = 0.f, w0 = 0.f, w1 = 0.f;
    for (; e + 3 < e1; e += 4) {
        int ia = edge_src[e],     ib = edge_src[e + 1];
        int ic = edge_src[e + 2], id = edge_src[e + 3];
        unsigned int va = f[ia * 64 + lane];
        unsigned int vb = f[ib * 64 + lane];
        unsigned int vc = f[ic * 64 + lane];
        unsigned int vd = f[id * 64 + lane];
        s0 += bflo(va); s1 += bfhi(va);
        t0 += bflo(vb); t1 += bfhi(vb);
        u0 += bflo(vc); u1 += bfhi(vc);
        w0 += bflo(vd); w1 += bfhi(vd);
    }
    for (; e < e1; ++e) {
        unsigned int va = f[edge_src[e] * 64 + lane];
        s0 += bflo(va); s1 += bfhi(va);
    }
    float lo = (s0 + t0) + (u0 + w0);
    float hi = (s1 + t1) + (u1 + w1);
    unsigned int o = (unsigned int)f2bf(lo) | ((unsigned int)f2bf(hi) << 16);
    ((unsigned int*)agg)[node * 64 + lane] = o;
}

// ===========================================================================
// MFMA GEMM:  H[n][j] = relu( [agg|x][n,0:256] . W[j,0:256] + b[j] )
// Block = 256 thr = 4 waves, 128 rows per block (wave: 2 row-tiles of 16).
// W staged as a straight 64KB memcpy from pre-packed bf16 Wb into LDS
// [kb][col][8] -- B-frag reads are contiguous 1KB/wave (conflict-free).
// B-frags reused across the 2 row-tiles. Barrier-free fully-unrolled K-loop.
// POOL: fused mean-pool numerator via run-compressed atomics (batch sorted;
// C-layout gives each lane 4 consecutive rows).
// ===========================================================================
template <bool POOL>
__global__ __launch_bounds__(256)
void gemm_mfma(const unsigned short* __restrict__ Aagg,
               const unsigned short* __restrict__ Ax,
               const unsigned short* __restrict__ Wb,   // one layer: 32768 bf16 = 64KB
               const float* __restrict__ bias,
               unsigned short* __restrict__ Hout,   // !POOL
               float* __restrict__ pooled,          // POOL
               const int* __restrict__ batch)       // POOL
{
    __shared__ __align__(16) unsigned short wlds[32768];  // 64KB, [kb][col][8]

    const int t = threadIdx.x;

    // ---- stage W: straight 64KB copy, 16B x 16 iters per thread ----
    {
        const uint4* s4 = (const uint4*)Wb;
        uint4* d4 = (uint4*)wlds;
#pragma unroll
        for (int i = 0; i < 16; ++i) d4[t + i * 256] = s4[t + i * 256];
    }
    __syncthreads();

    const int wave = t >> 6;
    const int lane = t & 63;
    const int q    = lane >> 4;                 // 0..3
    const int ln15 = lane & 15;
    const int m0   = blockIdx.x * 128 + wave * 16;   // tile0 rows; tile1 = +64

    int r0 = m0 + ln15;      int r0c = r0 < N_NODES ? r0 : N_NODES - 1;
    int r1 = m0 + 64 + ln15; int r1c = r1 < N_NODES ? r1 : N_NODES - 1;

    const unsigned short* A00 = Aagg + (size_t)r0c * DIM + q * 8;  // k 0..127
    const unsigned short* A01 = Ax   + (size_t)r0c * DIM + q * 8;  // k 128..255
    const unsigned short* A10 = Aagg + (size_t)r1c * DIM + q * 8;
    const unsigned short* A11 = Ax   + (size_t)r1c * DIM + q * 8;

    f32x4 acc0[8], acc1[8];
#pragma unroll
    for (int ct = 0; ct < 8; ++ct) {
        acc0[ct] = (f32x4){0.f, 0.f, 0.f, 0.f};
        acc1[ct] = (f32x4){0.f, 0.f, 0.f, 0.f};
    }

#pragma unroll
    for (int ks = 0; ks < 8; ++ks) {
        const unsigned short* p0 = (ks < 4) ? (A00 + ks * 32) : (A01 + (ks - 4) * 32);
        const unsigned short* p1 = (ks < 4) ? (A10 + ks * 32) : (A11 + (ks - 4) * 32);
        bf16x8 a0 = *(const bf16x8*)p0;
        bf16x8 a1 = *(const bf16x8*)p1;
        const unsigned short* wrow = wlds + (ks * 4 + q) * 1024;   // [kb][128][8]
#pragma unroll
        for (int ct = 0; ct < 8; ++ct) {
            bf16x8 bf = *(const bf16x8*)&wrow[(ct * 16 + ln15) * 8];
            acc0[ct] = __builtin_amdgcn_mfma_f32_16x16x32_bf16(a0, bf, acc0[ct], 0, 0, 0);
            acc1[ct] = __builtin_amdgcn_mfma_f32_16x16x32_bf16(a1, bf, acc1[ct], 0, 0, 0);
        }
    }

    float bj[8];
#pragma unroll
    for (int ct = 0; ct < 8; ++ct) bj[ct] = bias[ct * 16 + ln15];

#pragma unroll
    for (int rt = 0; rt < 2; ++rt) {
        const f32x4* acc = rt ? acc1 : acc0;
        const int rb = m0 + rt * 64 + q * 4;   // 4 consecutive rows

        if (!POOL) {
#pragma unroll
            for (int ct = 0; ct < 8; ++ct) {
                int coln = ct * 16 + ln15;
#pragma unroll
                for (int r = 0; r < 4; ++r) {
                    int row = rb + r;
                    if (row < N_NODES) {
                        float v = acc[ct][r] + bj[ct];
                        v = v > 0.f ? v : 0.f;
                        Hout[(size_t)row * DIM + coln] = f2bf(v);
                    }
                }
            }
        } else {
            int gg[4];
#pragma unroll
            for (int r = 0; r < 4; ++r) gg[r] = (rb + r < N_NODES) ? batch[rb + r] : -1;
            bool uni = (gg[0] == gg[3]) && (gg[3] >= 0);
#pragma unroll
            for (int ct = 0; ct < 8; ++ct) {
                int coln = ct * 16 + ln15;
                float v[4];
#pragma unroll
                for (int r = 0; r < 4; ++r) {
                    float x = acc[ct][r] + bj[ct];
                    v[r] = x > 0.f ? x : 0.f;
                }
                if (uni) {
                    atomicAdd(&pooled[gg[0] * DIM + coln], v[0] + v[1] + v[2] + v[3]);
                } else {
#pragma unroll
                    for (int r = 0; r < 4; ++r)
                        if (gg[r] >= 0) atomicAdd(&pooled[gg[r] * DIM + coln], v[r]);
                }
            }
        }
    }
}

// ===========================================================================
// out[g] = (pooled_sum[g]·W_out) / max(cnt_g,1) + b_out.  (all f32)
// ===========================================================================
__global__ void finalize_kernel(const float* __restrict__ pooled, const int* __restrict__ batch,
                                const float* __restrict__ Wout, const float* __restrict__ bout,
                                float* __restrict__ out)
{
    int g = blockIdx.x;
    int lane = threadIdx.x;  // 0..63

    int lo0 = 0, hi0 = N_NODES;
    while (lo0 < hi0) { int m = (lo0 + hi0) >> 1; if (batch[m] < g) lo0 = m + 1; else hi0 = m; }
    int lo1 = lo0, hi1 = N_NODES;
    while (lo1 < hi1) { int m = (lo1 + hi1) >> 1; if (batch[m] < g + 1) lo1 = m + 1; else hi1 = m; }
    int cnt = lo1 - lo0;

    float s = pooled[g * DIM + lane]      * Wout[lane]
            + pooled[g * DIM + 64 + lane] * Wout[64 + lane];
#pragma unroll
    for (int off = 32; off > 0; off >>= 1) s += __shfl_xor(s, off, 64);
    if (lane == 0) {
        float c = (float)(cnt > 1 ? cnt : 1);
        out[g] = s / c + bout[0];
    }
}

extern "C" void kernel_launch(void* const* d_in, const int* in_sizes, int n_in,
                              void* d_out, int out_size, void* d_ws, size_t ws_size,
                              hipStream_t stream)
{
    const float* x       = (const float*)d_in[0];
    const int*   ei      = (const int*)d_in[1];   // [2][E]: row 0 = src, row 1 = dst
    const int*   batch   = (const int*)d_in[2];
    const float* W1_rel  = (const float*)d_in[3];
    const float* W1_root = (const float*)d_in[4];
    const float* b1      = (const float*)d_in[5];
    const float* W2_rel  = (const float*)d_in[6];
    const float* W2_root = (const float*)d_in[7];
    const float* b2      = (const float*)d_in[8];
    const float* W_out   = (const float*)d_in[9];
    const float* b_out   = (const float*)d_in[10];
    float* out = (float*)d_out;

    const int* src  = ei;
    const int* dstv = ei + N_EDGES;

    // Workspace layout (bytes):
    //   aggb (bf16) @ 0          : 12,800,000
    //   xb   (bf16) @ 12,800,000 : 12,800,000
    //   h1b  (bf16) @ 25,600,000 : 12,800,000
    //   pooled f32  @ 38,400,000 :    131,072
    //   deg         @ 38,531,072 :    200,000
    //   row_ptr     @ 38,731,072 :    200,004
    //   edge_src    @ 38,931,200 :  2,000,000
    //   cursor      @ 40,931,200 :    200,000
    //   bsum        @ 41,131,200 :        512
    //   Wb  (bf16)  @ 41,131,712 :    131,072   (~41.3 MB)
    char* ws = (char*)d_ws;
    unsigned short* aggb = (unsigned short*)ws;
    unsigned short* xb   = (unsigned short*)(ws + 12800000);
    unsigned short* h1b  = (unsigned short*)(ws + 25600000);
    float* pooled        = (float*)(ws + 38400000);
    int*   deg           = (int*)  (ws + 38531072);
    int*   row_ptr       = (int*)  (ws + 38731072);
    int*   edge_src      = (int*)  (ws + 38931200);
    int*   cursor        = (int*)  (ws + 40931200);
    int*   bsum          = (int*)  (ws + 41131200);
    unsigned short* Wb   = (unsigned short*)(ws + 41131712);

    // ---- CSR build + conversions ----
    hipMemsetAsync(deg, 0, N_NODES * sizeof(int), stream);
    hipMemsetAsync(pooled, 0, N_GRAPHS * DIM * sizeof(float), stream);
    cvt_kernel       <<<(N_NODES * DIM / 4) / 256, 256, 0, stream>>>(x, xb);
    wcvt_kernel      <<<32, 256, 0, stream>>>(W1_rel, W1_root, W2_rel, W2_root, Wb);
    hist_kernel      <<<(N_EDGES + 255) / 256, 256, 0, stream>>>(dstv, deg);
    block_sum_kernel <<<SCAN_NB, SCAN_B, 0, stream>>>(deg, bsum);
    scan_sums_kernel <<<1, 128, 0, stream>>>(bsum);
    scan_apply_kernel<<<SCAN_NB, SCAN_B, 0, stream>>>(deg, bsum, row_ptr, cursor);
    build_kernel     <<<(N_EDGES + 255) / 256, 256, 0, stream>>>(src, dstv, cursor, edge_src);

    const int gemm_grid = (N_NODES + 127) / 128;   // 391

    // ---- Layer 1 ----
    gather_kernel<<<N_NODES / 4, 256, 0, stream>>>(xb, row_ptr, edge_src, aggb);
    gemm_mfma<false><<<gemm_grid, 256, 0, stream>>>(
        aggb, xb, Wb, b1, h1b, nullptr, nullptr);

    // ---- Layer 2 (+ fused mean-pool numerator) ----
    gather_kernel<<<N_NODES / 4, 256, 0, stream>>>(h1b, row_ptr, edge_src, aggb);
    gemm_mfma<true><<<gemm_grid, 256, 0, stream>>>(
        aggb, h1b, Wb + 32768, b2, nullptr, pooled, batch);

    // ---- Output head ----
    finalize_kernel<<<N_GRAPHS, 64, 0, stream>>>(pooled, batch, W_out, b_out, out);
}

// Round 8
// 242.830 us; speedup vs baseline: 3.6327x; 1.0027x over previous
//
#include <hip/hip_runtime.h>
#include <hip/hip_bf16.h>

#define N_NODES  50000
#define N_EDGES  500000
#define DIM      128
#define N_GRAPHS 256

#define SCAN_B   512
#define SCAN_NB  ((N_NODES + SCAN_B - 1) / SCAN_B)   // 98

// prep_kernel block partition
#define PB_CVT   6250                      // x -> bf16: 1.6M float4 / 256
#define PB_W     32                        // weights -> packed bf16: 8192 thr
#define PB_DEG   ((N_NODES + 255) / 256)   // zero deg: 196
#define PB_POOL  128                       // zero pooled: 32768 f32 / 256
#define PB_TOTAL (PB_CVT + PB_W + PB_DEG + PB_POOL)

typedef __attribute__((ext_vector_type(8))) short bf16x8;
typedef __attribute__((ext_vector_type(4))) float f32x4;

__device__ __forceinline__ unsigned short f2bf(float f) {
    __hip_bfloat16 h = __float2bfloat16(f);          // RNE
    return *(unsigned short*)&h;
}
__device__ __forceinline__ float bflo(unsigned int v) { return __uint_as_float(v << 16); }
__device__ __forceinline__ float bfhi(unsigned int v) { return __uint_as_float(v & 0xffff0000u); }

// ===========================================================================
// Fused prep: [0,6250) x->bf16 | [6250,6282) weights->packed bf16
//           | [.., +196) zero deg | [.., +128) zero pooled
// ===========================================================================
__global__ __launch_bounds__(256)
void prep_kernel(const float* __restrict__ x,
                 const float* __restrict__ W1_rel, const float* __restrict__ W1_root,
                 const float* __restrict__ W2_rel, const float* __restrict__ W2_root,
                 unsigned short* __restrict__ xb, unsigned short* __restrict__ Wb,
                 int* __restrict__ deg, float* __restrict__ pooled)
{
    int b = blockIdx.x, t = threadIdx.x;
    if (b < PB_CVT) {
        int i = b * 256 + t;
        float4 v = ((const float4*)x)[i];
        ushort4 o;
        o.x = f2bf(v.x); o.y = f2bf(v.y); o.z = f2bf(v.z); o.w = f2bf(v.w);
        ((ushort4*)xb)[i] = o;
    } else if (b < PB_CVT + PB_W) {
        int u = (b - PB_CVT) * 256 + t;      // 0..8191
        int layer = u >> 12;
        int kb    = (u >> 7) & 31;
        int col   = u & 127;
        int k0    = kb * 8;
        const float* Wrel  = layer ? W2_rel  : W1_rel;
        const float* Wroot = layer ? W2_root : W1_root;
        const float* srcp = (k0 < 128) ? (Wrel + col * 128 + k0)
                                       : (Wroot + col * 128 + (k0 - 128));
        float4 v0 = ((const float4*)srcp)[0];
        float4 v1 = ((const float4*)srcp)[1];
        ushort4 o0, o1;
        o0.x = f2bf(v0.x); o0.y = f2bf(v0.y); o0.z = f2bf(v0.z); o0.w = f2bf(v0.w);
        o1.x = f2bf(v1.x); o1.y = f2bf(v1.y); o1.z = f2bf(v1.z); o1.w = f2bf(v1.w);
        unsigned short* dst = Wb + (size_t)layer * 32768 + ((kb * 128 + col) * 8);
        ((ushort4*)dst)[0] = o0;
        ((ushort4*)dst)[1] = o1;
    } else if (b < PB_CVT + PB_W + PB_DEG) {
        int i = (b - PB_CVT - PB_W) * 256 + t;
        if (i < N_NODES) deg[i] = 0;
    } else {
        int i = (b - PB_CVT - PB_W - PB_DEG) * 256 + t;   // < 32768 exactly
        pooled[i] = 0.f;
    }
}

// ===========================================================================
// CSR build (edge list identical for both layers -> build once per call)
// ===========================================================================
__global__ void hist_kernel(const int* __restrict__ dst, int* __restrict__ deg)
{
    int e = blockIdx.x * blockDim.x + threadIdx.x;
    if (e < N_EDGES) atomicAdd(&deg[dst[e]], 1);
}

__global__ __launch_bounds__(SCAN_B)
void block_sum_kernel(const int* __restrict__ deg, int* __restrict__ bsum)
{
    __shared__ int red[SCAN_B];
    int t = threadIdx.x;
    int idx = blockIdx.x * SCAN_B + t;
    red[t] = (idx < N_NODES) ? deg[idx] : 0;
    __syncthreads();
    for (int off = SCAN_B / 2; off > 0; off >>= 1) {
        if (t < off) red[t] += red[t + off];
        __syncthreads();
    }
    if (t == 0) bsum[blockIdx.x] = red[0];
}

__global__ __launch_bounds__(128)
void scan_sums_kernel(int* __restrict__ bsum)   // in-place -> exclusive prefix
{
    __shared__ int s[128];
    int t = threadIdx.x;
    int v = (t < SCAN_NB) ? bsum[t] : 0;
    s[t] = v;
    __syncthreads();
    for (int off = 1; off < 128; off <<= 1) {
        int u = (t >= off) ? s[t - off] : 0;
        __syncthreads();
        s[t] += u;
        __syncthreads();
    }
    if (t < SCAN_NB) bsum[t] = s[t] - v;
}

__global__ __launch_bounds__(SCAN_B)
void scan_apply_kernel(const int* __restrict__ deg, const int* __restrict__ bsum,
                       int* __restrict__ row_ptr, int* __restrict__ cursor)
{
    __shared__ int s[SCAN_B];
    int t = threadIdx.x;
    int idx = blockIdx.x * SCAN_B + t;
    int v = (idx < N_NODES) ? deg[idx] : 0;
    s[t] = v;
    __syncthreads();
    for (int off = 1; off < SCAN_B; off <<= 1) {
        int u = (t >= off) ? s[t - off] : 0;
        __syncthreads();
        s[t] += u;
        __syncthreads();
    }
    if (idx < N_NODES) {
        int ex = bsum[blockIdx.x] + s[t] - v;
        row_ptr[idx] = ex;
        cursor[idx]  = ex;
    }
    if (idx == 0) row_ptr[N_NODES] = N_EDGES;
}

__global__ void build_kernel(const int* __restrict__ src, const int* __restrict__ dst,
                             int* __restrict__ cursor, int* __restrict__ edge_src)
{
    int e = blockIdx.x * blockDim.x + threadIdx.x;
    if (e < N_EDGES) {
        int pos = atomicAdd(&cursor[dst[e]], 1);
        edge_src[pos] = src[e];
    }
}

// ===========================================================================
// Gather-aggregate (bf16 feat -> bf16 agg, f32 accumulate in-register).
// One wave per node; HALF-WAVE per edge: lanes 0-31 even edges, 32-63 odd
// edges, each lane holds 4 features (uint2 = 8B -> 32 lanes cover the row).
// 4-pair unroll = 8 row-loads in flight. Final shfl_xor(32) cross-half sum.
// ===========================================================================
__global__ __launch_bounds__(256)
void gather_kernel(const unsigned short* __restrict__ feat,
                   const int* __restrict__ row_ptr,
                   const int* __restrict__ edge_src,
                   unsigned short* __restrict__ agg)
{
    int wid  = (blockIdx.x * blockDim.x + threadIdx.x) >> 6;
    int lane = threadIdx.x & 63;
    int node = __builtin_amdgcn_readfirstlane(wid);
    int half = lane >> 5;          // 0: even edges, 1: odd edges
    int l31  = lane & 31;

    const uint2* f = (const uint2*)feat;   // 4 bf16 per uint2; 32 per row
    int e  = row_ptr[node];
    int e1 = row_ptr[node + 1];

    float a0 = 0.f, a1 = 0.f, a2 = 0.f, a3 = 0.f;
    float b0 = 0.f, b1 = 0.f, b2 = 0.f, b3 = 0.f;

    for (; e + 7 < e1; e += 8) {           // 8 edges per iter (4 pairs)
#pragma unroll
        for (int p = 0; p < 4; ++p) {
            int idx = edge_src[e + p * 2 + half];
            uint2 v = f[idx * 32 + l31];
            if (p & 1) {
                b0 += bflo(v.x); b1 += bfhi(v.x); b2 += bflo(v.y); b3 += bfhi(v.y);
            } else {
                a0 += bflo(v.x); a1 += bfhi(v.x); a2 += bflo(v.y); a3 += bfhi(v.y);
            }
        }
    }
    for (; e < e1; e += 2) {               // tail: 1-2 edges per iter
        int my = e + half;
        if (my < e1) {
            uint2 v = f[edge_src[my] * 32 + l31];
            a0 += bflo(v.x); a1 += bfhi(v.x); a2 += bflo(v.y); a3 += bfhi(v.y);
        }
    }
    a0 += b0; a1 += b1; a2 += b2; a3 += b3;
    a0 += __shfl_xor(a0, 32, 64);
    a1 += __shfl_xor(a1, 32, 64);
    a2 += __shfl_xor(a2, 32, 64);
    a3 += __shfl_xor(a3, 32, 64);
    if (half == 0) {
        uint2 o;
        o.x = (unsigned)f2bf(a0) | ((unsigned)f2bf(a1) << 16);
        o.y = (unsigned)f2bf(a2) | ((unsigned)f2bf(a3) << 16);
        ((uint2*)agg)[node * 32 + l31] = o;
    }
}

// ===========================================================================
// MFMA GEMM:  H[n][j] = relu( [agg|x][n,0:256] . W[j,0:256] + b[j] )
// Block = 256 thr = 4 waves, 128 rows per block (wave: 2 row-tiles of 16).
// W staged as a straight 64KB memcpy from pre-packed bf16 Wb into LDS
// [kb][col][8] -- B-frag reads are contiguous 1KB/wave (conflict-free).
// POOL: fused mean-pool numerator via run-compressed atomics (batch sorted).
// ===========================================================================
template <bool POOL>
__global__ __launch_bounds__(256)
void gemm_mfma(const unsigned short* __restrict__ Aagg,
               const unsigned short* __restrict__ Ax,
               const unsigned short* __restrict__ Wb,   // one layer: 64KB
               const float* __restrict__ bias,
               unsigned short* __restrict__ Hout,   // !POOL
               float* __restrict__ pooled,          // POOL
               const int* __restrict__ batch)       // POOL
{
    __shared__ __align__(16) unsigned short wlds[32768];  // 64KB, [kb][col][8]

    const int t = threadIdx.x;

    {
        const uint4* s4 = (const uint4*)Wb;
        uint4* d4 = (uint4*)wlds;
#pragma unroll
        for (int i = 0; i < 16; ++i) d4[t + i * 256] = s4[t + i * 256];
    }
    __syncthreads();

    const int wave = t >> 6;
    const int lane = t & 63;
    const int q    = lane >> 4;                 // 0..3
    const int ln15 = lane & 15;
    const int m0   = blockIdx.x * 128 + wave * 16;   // tile0 rows; tile1 = +64

    int r0 = m0 + ln15;      int r0c = r0 < N_NODES ? r0 : N_NODES - 1;
    int r1 = m0 + 64 + ln15; int r1c = r1 < N_NODES ? r1 : N_NODES - 1;

    const unsigned short* A00 = Aagg + (size_t)r0c * DIM + q * 8;  // k 0..127
    const unsigned short* A01 = Ax   + (size_t)r0c * DIM + q * 8;  // k 128..255
    const unsigned short* A10 = Aagg + (size_t)r1c * DIM + q * 8;
    const unsigned short* A11 = Ax   + (size_t)r1c * DIM + q * 8;

    f32x4 acc0[8], acc1[8];
#pragma unroll
    for (int ct = 0; ct < 8; ++ct) {
        acc0[ct] = (f32x4){0.f, 0.f, 0.f, 0.f};
        acc1[ct] = (f32x4){0.f, 0.f, 0.f, 0.f};
    }

#pragma unroll
    for (int ks = 0; ks < 8; ++ks) {
        const unsigned short* p0 = (ks < 4) ? (A00 + ks * 32) : (A01 + (ks - 4) * 32);
        const unsigned short* p1 = (ks < 4) ? (A10 + ks * 32) : (A11 + (ks - 4) * 32);
        bf16x8 a0 = *(const bf16x8*)p0;
        bf16x8 a1 = *(const bf16x8*)p1;
        const unsigned short* wrow = wlds + (ks * 4 + q) * 1024;   // [kb][128][8]
#pragma unroll
        for (int ct = 0; ct < 8; ++ct) {
            bf16x8 bf = *(const bf16x8*)&wrow[(ct * 16 + ln15) * 8];
            acc0[ct] = __builtin_amdgcn_mfma_f32_16x16x32_bf16(a0, bf, acc0[ct], 0, 0, 0);
            acc1[ct] = __builtin_amdgcn_mfma_f32_16x16x32_bf16(a1, bf, acc1[ct], 0, 0, 0);
        }
    }

    float bj[8];
#pragma unroll
    for (int ct = 0; ct < 8; ++ct) bj[ct] = bias[ct * 16 + ln15];

#pragma unroll
    for (int rt = 0; rt < 2; ++rt) {
        const f32x4* acc = rt ? acc1 : acc0;
        const int rb = m0 + rt * 64 + q * 4;   // 4 consecutive rows

        if (!POOL) {
#pragma unroll
            for (int ct = 0; ct < 8; ++ct) {
                int coln = ct * 16 + ln15;
#pragma unroll
                for (int r = 0; r < 4; ++r) {
                    int row = rb + r;
                    if (row < N_NODES) {
                        float v = acc[ct][r] + bj[ct];
                        v = v > 0.f ? v : 0.f;
                        Hout[(size_t)row * DIM + coln] = f2bf(v);
                    }
                }
            }
        } else {
            int gg[4];
#pragma unroll
            for (int r = 0; r < 4; ++r) gg[r] = (rb + r < N_NODES) ? batch[rb + r] : -1;
            bool uni = (gg[0] == gg[3]) && (gg[3] >= 0);
#pragma unroll
            for (int ct = 0; ct < 8; ++ct) {
                int coln = ct * 16 + ln15;
                float v[4];
#pragma unroll
                for (int r = 0; r < 4; ++r) {
                    float x = acc[ct][r] + bj[ct];
                    v[r] = x > 0.f ? x : 0.f;
                }
                if (uni) {
                    atomicAdd(&pooled[gg[0] * DIM + coln], v[0] + v[1] + v[2] + v[3]);
                } else {
#pragma unroll
                    for (int r = 0; r < 4; ++r)
                        if (gg[r] >= 0) atomicAdd(&pooled[gg[r] * DIM + coln], v[r]);
                }
            }
        }
    }
}

// ===========================================================================
// out[g] = (pooled_sum[g]·W_out) / max(cnt_g,1) + b_out.  (all f32)
// ===========================================================================
__global__ void finalize_kernel(const float* __restrict__ pooled, const int* __restrict__ batch,
                                const float* __restrict__ Wout, const float* __restrict__ bout,
                                float* __restrict__ out)
{
    int g = blockIdx.x;
    int lane = threadIdx.x;  // 0..63

    int lo0 = 0, hi0 = N_NODES;
    while (lo0 < hi0) { int m = (lo0 + hi0) >> 1; if (batch[m] < g) lo0 = m + 1; else hi0 = m; }
    int lo1 = lo0, hi1 = N_NODES;
    while (lo1 < hi1) { int m = (lo1 + hi1) >> 1; if (batch[m] < g + 1) lo1 = m + 1; else hi1 = m; }
    int cnt = lo1 - lo0;

    float s = pooled[g * DIM + lane]      * Wout[lane]
            + pooled[g * DIM + 64 + lane] * Wout[64 + lane];
#pragma unroll
    for (int off = 32; off > 0; off >>= 1) s += __shfl_xor(s, off, 64);
    if (lane == 0) {
        float c = (float)(cnt > 1 ? cnt : 1);
        out[g] = s / c + bout[0];
    }
}

extern "C" void kernel_launch(void* const* d_in, const int* in_sizes, int n_in,
                              void* d_out, int out_size, void* d_ws, size_t ws_size,
                              hipStream_t stream)
{
    const float* x       = (const float*)d_in[0];
    const int*   ei      = (const int*)d_in[1];   // [2][E]: row 0 = src, row 1 = dst
    const int*   batch   = (const int*)d_in[2];
    const float* W1_rel  = (const float*)d_in[3];
    const float* W1_root = (const float*)d_in[4];
    const float* b1      = (const float*)d_in[5];
    const float* W2_rel  = (const float*)d_in[6];
    const float* W2_root = (const float*)d_in[7];
    const float* b2      = (const float*)d_in[8];
    const float* W_out   = (const float*)d_in[9];
    const float* b_out   = (const float*)d_in[10];
    float* out = (float*)d_out;

    const int* src  = ei;
    const int* dstv = ei + N_EDGES;

    // Workspace layout (bytes):
    //   aggb (bf16) @ 0          : 12,800,000
    //   xb   (bf16) @ 12,800,000 : 12,800,000
    //   h1b  (bf16) @ 25,600,000 : 12,800,000
    //   pooled f32  @ 38,400,000 :    131,072
    //   deg         @ 38,531,072 :    200,000
    //   row_ptr     @ 38,731,072 :    200,004
    //   edge_src    @ 38,931,200 :  2,000,000
    //   cursor      @ 40,931,200 :    200,000
    //   bsum        @ 41,131,200 :        512
    //   Wb  (bf16)  @ 41,131,712 :    131,072   (~41.3 MB)
    char* ws = (char*)d_ws;
    unsigned short* aggb = (unsigned short*)ws;
    unsigned short* xb   = (unsigned short*)(ws + 12800000);
    unsigned short* h1b  = (unsigned short*)(ws + 25600000);
    float* pooled        = (float*)(ws + 38400000);
    int*   deg           = (int*)  (ws + 38531072);
    int*   row_ptr       = (int*)  (ws + 38731072);
    int*   edge_src      = (int*)  (ws + 38931200);
    int*   cursor        = (int*)  (ws + 40931200);
    int*   bsum          = (int*)  (ws + 41131200);
    unsigned short* Wb   = (unsigned short*)(ws + 41131712);

    // ---- fused prep (cvt x, cvt W, zero deg, zero pooled) + CSR build ----
    prep_kernel      <<<PB_TOTAL, 256, 0, stream>>>(x, W1_rel, W1_root, W2_rel, W2_root,
                                                    xb, Wb, deg, pooled);
    hist_kernel      <<<(N_EDGES + 255) / 256, 256, 0, stream>>>(dstv, deg);
    block_sum_kernel <<<SCAN_NB, SCAN_B, 0, stream>>>(deg, bsum);
    scan_sums_kernel <<<1, 128, 0, stream>>>(bsum);
    scan_apply_kernel<<<SCAN_NB, SCAN_B, 0, stream>>>(deg, bsum, row_ptr, cursor);
    build_kernel     <<<(N_EDGES + 255) / 256, 256, 0, stream>>>(src, dstv, cursor, edge_src);

    const int gemm_grid = (N_NODES + 127) / 128;   // 391

    // ---- Layer 1 ----
    gather_kernel<<<N_NODES / 4, 256, 0, stream>>>(xb, row_ptr, edge_src, aggb);
    gemm_mfma<false><<<gemm_grid, 256, 0, stream>>>(
        aggb, xb, Wb, b1, h1b, nullptr, nullptr);

    // ---- Layer 2 (+ fused mean-pool numerator) ----
    gather_kernel<<<N_NODES / 4, 256, 0, stream>>>(h1b, row_ptr, edge_src, aggb);
    gemm_mfma<true><<<gemm_grid, 256, 0, stream>>>(
        aggb, h1b, Wb + 32768, b2, nullptr, pooled, batch);

    // ---- Output head ----
    finalize_kernel<<<N_GRAPHS, 64, 0, stream>>>(pooled, batch, W_out, b_out, out);
}